// Round 7
// baseline (42.248 us; speedup 1.0000x reference)
//
#include <hip/hip_runtime.h>
#include <math.h>

#define T_SAMPLES 100
#define K1_BLOCKS 1024
#define T1 256
#define NB2 256            // K2 blocks (1/CU, 16 waves each)
#define T2 1024            // K2 threads
#define NSUB 16            // sub-histogram per lane&15 (4 lanes/wave share one)
#define HPAD 101           // odd stride -> 16 subs on distinct banks
#define PART 4096          // u32 index: block b's cnt at [b*256+j], ofs at [b*256+128+j]
#define CNT_SHIFT 22
#define OFS_MASK ((1u << 22) - 1u)
// pack: count bits[22:31] (<=512 per sub worst case, 10 bits ok),
//       ofs = floor(frac*8192) <= 8191, sum per sub <= 512*8191 < 2^22  ✓
// ws footprint: (4096 + 256*256)*4 = 278.5 KB  (<= known-good 430 KB from R6)

__global__ void __launch_bounds__(T1) cvar_pass1(const float* __restrict__ pnl,
                                                 int n, float* __restrict__ ws) {
    if (blockIdx.x == 0 && threadIdx.x == 0) ((unsigned*)ws)[0] = 0u;  // K2 counter

    int tid = blockIdx.x * T1 + threadIdx.x;
    int stride = gridDim.x * T1;
    float lmin = INFINITY, lmax = -INFINITY;
    int n4 = n >> 2;
    const float4* p4 = (const float4*)pnl;
    for (int i = tid; i < n4; i += stride) {
        float4 v = p4[i];
        lmin = fminf(lmin, fminf(fminf(-v.x, -v.y), fminf(-v.z, -v.w)));
        lmax = fmaxf(lmax, fmaxf(fmaxf(-v.x, -v.y), fmaxf(-v.z, -v.w)));
    }
    for (int i = (n4 << 2) + tid; i < n; i += stride) {
        float l = -pnl[i];
        lmin = fminf(lmin, l);
        lmax = fmaxf(lmax, l);
    }
    #pragma unroll
    for (int off = 32; off > 0; off >>= 1) {
        lmin = fminf(lmin, __shfl_down(lmin, off, 64));
        lmax = fmaxf(lmax, __shfl_down(lmax, off, 64));
    }
    __shared__ float smin[T1 / 64], smax[T1 / 64];
    int lane = threadIdx.x & 63, wid = threadIdx.x >> 6;
    if (lane == 0) { smin[wid] = lmin; smax[wid] = lmax; }
    __syncthreads();
    if (threadIdx.x == 0) {
        float a = smin[0], b = smax[0];
        for (int w = 1; w < T1 / 64; ++w) { a = fminf(a, smin[w]); b = fmaxf(b, smax[w]); }
        ws[16 + blockIdx.x] = a;
        ws[16 + K1_BLOCKS + blockIdx.x] = b;
    }
}

__global__ void __launch_bounds__(T2) cvar_pass2(const float* __restrict__ pnl,
                                                 int n, float* __restrict__ ws,
                                                 float* __restrict__ out) {
    __shared__ unsigned h[NSUB * HPAD];
    __shared__ float smin[T2 / 64], smax[T2 / 64];
    __shared__ float s_tmin, s_tmax;
    __shared__ bool amLast;
    __shared__ double dcnt[T_SAMPLES], dofs[T_SAMPLES];
    __shared__ float sred[T2 / 64];

    for (int i = threadIdx.x; i < NSUB * HPAD; i += T2) h[i] = 0u;

    // finish the min/max reduce: exactly 1 partial pair per thread
    {
        float lmin = ws[16 + threadIdx.x];
        float lmax = ws[16 + K1_BLOCKS + threadIdx.x];
        #pragma unroll
        for (int off = 32; off > 0; off >>= 1) {
            lmin = fminf(lmin, __shfl_down(lmin, off, 64));
            lmax = fmaxf(lmax, __shfl_down(lmax, off, 64));
        }
        int lane = threadIdx.x & 63, wid = threadIdx.x >> 6;
        if (lane == 0) { smin[wid] = lmin; smax[wid] = lmax; }
        __syncthreads();
        if (threadIdx.x == 0) {
            float a = smin[0], b = smax[0];
            for (int w = 1; w < T2 / 64; ++w) { a = fminf(a, smin[w]); b = fmaxf(b, smax[w]); }
            s_tmin = a;
            s_tmax = b;
        }
        __syncthreads();
    }

    const float t_min = s_tmin, t_max = s_tmax;
    const float range = t_max - t_min;
    const float inv_dt = (range > 0.0f) ? (float)(T_SAMPLES - 1) / range : 0.0f;

    // LDS histogram: <=8 elements/thread, sub keyed by lane&15
    const int subbase = (threadIdx.x & 15) * HPAD;
    int tid = blockIdx.x * T2 + threadIdx.x;
    int stride = NB2 * T2;
    int n4 = n >> 2;
    const float4* p4 = (const float4*)pnl;
    for (int i = tid; i < n4; i += stride) {
        float4 v = p4[i];
        float l[4] = {-v.x, -v.y, -v.z, -v.w};
        #pragma unroll
        for (int k = 0; k < 4; ++k) {
            float x = (l[k] - t_min) * inv_dt;
            int b = (int)x;
            b = b < 0 ? 0 : (b > T_SAMPLES - 1 ? T_SAMPLES - 1 : b);
            unsigned of = (unsigned)(fminf(x - (float)b, 0.99987793f) * 8192.0f);
            atomicAdd(&h[subbase + b], (1u << CNT_SHIFT) | of);
        }
    }
    for (int i = (n4 << 2) + tid; i < n; i += stride) {
        float x = (-pnl[i] - t_min) * inv_dt;
        int b = (int)x;
        b = b < 0 ? 0 : (b > T_SAMPLES - 1 ? T_SAMPLES - 1 : b);
        unsigned of = (unsigned)(fminf(x - (float)b, 0.99987793f) * 8192.0f);
        atomicAdd(&h[subbase + b], (1u << CNT_SHIFT) | of);
    }
    __syncthreads();

    // merge 16 subs (split fields) -> CONTIGUOUS per-block slot (coalesced store)
    if (threadIdx.x < T_SAMPLES) {
        unsigned cnt = 0u, ofs = 0u;
        #pragma unroll
        for (int s = 0; s < NSUB; ++s) {
            unsigned p = h[s * HPAD + threadIdx.x];
            cnt += p >> CNT_SHIFT;
            ofs += p & OFS_MASK;
        }
        unsigned* part = (unsigned*)ws + PART + blockIdx.x * 256;
        __hip_atomic_store(&part[threadIdx.x], cnt,
                           __ATOMIC_RELAXED, __HIP_MEMORY_SCOPE_AGENT);
        __hip_atomic_store(&part[128 + threadIdx.x], ofs,
                           __ATOMIC_RELAXED, __HIP_MEMORY_SCOPE_AGENT);
    }
    __syncthreads();

    if (threadIdx.x == 0) {
        __threadfence();
        unsigned prev = atomicAdd((unsigned*)ws, 1u);
        amLast = (prev == NB2 - 1);
    }
    __syncthreads();
    if (!amLast) return;
    __threadfence();

    // last block: 8 threads/bin, 32 independent loads each per plane (MLP-covered)
    int g = threadIdx.x >> 3, q = threadIdx.x & 7;
    unsigned long long c64 = 0ull, o64 = 0ull;
    if (g < T_SAMPLES) {
        const unsigned* base = (const unsigned*)ws + PART;
        for (int b = q; b < NB2; b += 8) {
            c64 += __hip_atomic_load(base + b * 256 + g,
                                     __ATOMIC_RELAXED, __HIP_MEMORY_SCOPE_AGENT);
            o64 += __hip_atomic_load(base + b * 256 + 128 + g,
                                     __ATOMIC_RELAXED, __HIP_MEMORY_SCOPE_AGENT);
        }
    }
    #pragma unroll
    for (int off = 4; off > 0; off >>= 1) {
        c64 += __shfl_down(c64, off, 8);
        o64 += __shfl_down(o64, off, 8);
    }
    if (g < T_SAMPLES && q == 0) { dcnt[g] = (double)c64; dofs[g] = (double)o64; }
    __syncthreads();

    const float dt = range / (float)(T_SAMPLES - 1);
    float cvar = INFINITY;
    int j = threadIdx.x;
    if (j < T_SAMPLES) {
        double O = 0.0, W = 0.0;
        for (int k = j; k < T_SAMPLES; ++k) {
            O += dofs[k];
            W += (double)(k - j) * dcnt[k];
        }
        // S(t_j) = dt * ( sum(frac)/2^13 + sum (k-j)*C_k )
        double S = (double)dt * (O * (1.0 / 8192.0) + W);
        float tj = (j == T_SAMPLES - 1) ? t_max : t_min + (float)j * dt;
        cvar = tj + (float)(S * (20.0 / (double)n));
    }
    #pragma unroll
    for (int off = 32; off > 0; off >>= 1)
        cvar = fminf(cvar, __shfl_down(cvar, off, 64));
    int lane = threadIdx.x & 63, wid = threadIdx.x >> 6;
    if (lane == 0) sred[wid] = cvar;
    __syncthreads();
    if (threadIdx.x == 0) {
        float m = sred[0];
        for (int w = 1; w < T2 / 64; ++w) m = fminf(m, sred[w]);
        out[0] = m;
    }
}

extern "C" void kernel_launch(void* const* d_in, const int* in_sizes, int n_in,
                              void* d_out, int out_size, void* d_ws, size_t ws_size,
                              hipStream_t stream) {
    const float* pnl = (const float*)d_in[0];
    int n = in_sizes[0];
    float* ws = (float*)d_ws;
    float* out = (float*)d_out;

    cvar_pass1<<<K1_BLOCKS, T1, 0, stream>>>(pnl, n, ws);
    cvar_pass2<<<NB2, T2, 0, stream>>>(pnl, n, ws, out);
}

// Round 8
// 38.208 us; speedup vs baseline: 1.1057x; 1.1057x over previous
//
#include <hip/hip_runtime.h>
#include <math.h>

#define T_SAMPLES 100
#define K1_BLOCKS 1024
#define HB 1024           // hist blocks (R5-proven shape)
#define THREADS 256
#define NWAVES (THREADS / 64)
#define NSUB 16           // sub-histogram per lane&15 (4 lanes/wave share one)
#define HPAD 101          // odd stride -> 16 subs on distinct banks
#define CNT_SHIFT 22      // LDS pack: count bits[22:31], frac*2^13 bits[0:21]
#define OFS_MASK ((1u << 22) - 1u)
#define NCOPY 64          // global slot copies (contention = HB/NCOPY = 16/addr)
#define SLOT_STRIDE 128   // u64 per copy region (128*8=1KB, no false sharing)
#define SLOTS64 2048      // u64 index where slot copies start
#define GSHIFT 43         // global pack: cnt bits[43:63], ofs bits[0:42]
#define GMASK ((1ull << GSHIFT) - 1ull)
// per-sub LDS overflow: 16 thr/sub * 8 elems = 128 cnt (<2^10), ofs<128*8191<2^20 OK
// per-slot global: 16 blocks * (cnt<=2048, ofs<2^25) -> cnt<2^15, ofs<2^29 OK
// ws: u32 counter[0]; f[16..2064) minmax partials; u64[2048..2048+64*128) slots = 81KB

__global__ void __launch_bounds__(THREADS) cvar_pass1(const float* __restrict__ pnl,
                                                      int n, float* __restrict__ ws) {
    // zero K2's counter + slot copies (stream-ordered before K2)
    if (blockIdx.x == 0) {
        if (threadIdx.x == 0) ((unsigned*)ws)[0] = 0u;
        unsigned long long* slots = (unsigned long long*)ws + SLOTS64;
        for (int i = threadIdx.x; i < NCOPY * SLOT_STRIDE; i += THREADS) slots[i] = 0ull;
    }

    int tid = blockIdx.x * THREADS + threadIdx.x;
    int stride = gridDim.x * THREADS;
    float lmin = INFINITY, lmax = -INFINITY;
    int n4 = n >> 2;
    const float4* p4 = (const float4*)pnl;
    for (int i = tid; i < n4; i += stride) {
        float4 v = p4[i];
        lmin = fminf(lmin, fminf(fminf(-v.x, -v.y), fminf(-v.z, -v.w)));
        lmax = fmaxf(lmax, fmaxf(fmaxf(-v.x, -v.y), fmaxf(-v.z, -v.w)));
    }
    for (int i = (n4 << 2) + tid; i < n; i += stride) {
        float l = -pnl[i];
        lmin = fminf(lmin, l);
        lmax = fmaxf(lmax, l);
    }
    #pragma unroll
    for (int off = 32; off > 0; off >>= 1) {
        lmin = fminf(lmin, __shfl_down(lmin, off, 64));
        lmax = fmaxf(lmax, __shfl_down(lmax, off, 64));
    }
    __shared__ float smin[NWAVES], smax[NWAVES];
    int lane = threadIdx.x & 63, wid = threadIdx.x >> 6;
    if (lane == 0) { smin[wid] = lmin; smax[wid] = lmax; }
    __syncthreads();
    if (threadIdx.x == 0) {
        float a = smin[0], b = smax[0];
        for (int w = 1; w < NWAVES; ++w) { a = fminf(a, smin[w]); b = fmaxf(b, smax[w]); }
        ws[16 + blockIdx.x] = a;
        ws[16 + K1_BLOCKS + blockIdx.x] = b;
    }
}

__global__ void __launch_bounds__(THREADS) cvar_pass2(const float* __restrict__ pnl,
                                                      int n, float* __restrict__ ws,
                                                      float* __restrict__ out) {
    __shared__ unsigned h[NSUB * HPAD];
    __shared__ float smin[NWAVES], smax[NWAVES];
    __shared__ float s_tmin, s_tmax;
    __shared__ bool amLast;
    __shared__ double dcnt[T_SAMPLES], dofs[T_SAMPLES];
    __shared__ float sred[NWAVES];

    for (int i = threadIdx.x; i < NSUB * HPAD; i += THREADS) h[i] = 0u;

    // reduce the 1024 min/max partials (L2-resident, 8 loads/thread)
    {
        float lmin = INFINITY, lmax = -INFINITY;
        for (int i = threadIdx.x; i < K1_BLOCKS; i += THREADS) {
            lmin = fminf(lmin, ws[16 + i]);
            lmax = fmaxf(lmax, ws[16 + K1_BLOCKS + i]);
        }
        #pragma unroll
        for (int off = 32; off > 0; off >>= 1) {
            lmin = fminf(lmin, __shfl_down(lmin, off, 64));
            lmax = fmaxf(lmax, __shfl_down(lmax, off, 64));
        }
        int lane = threadIdx.x & 63, wid = threadIdx.x >> 6;
        if (lane == 0) { smin[wid] = lmin; smax[wid] = lmax; }
        __syncthreads();
        if (threadIdx.x == 0) {
            float a = smin[0], b = smax[0];
            for (int w = 1; w < NWAVES; ++w) { a = fminf(a, smin[w]); b = fmaxf(b, smax[w]); }
            s_tmin = a;
            s_tmax = b;
        }
        __syncthreads();
    }

    const float t_min = s_tmin, t_max = s_tmax;
    const float range = t_max - t_min;
    const float inv_dt = (range > 0.0f) ? (float)(T_SAMPLES - 1) / range : 0.0f;

    // LDS histogram (R5-proven): 8 elems/thread, sub keyed by lane&15
    const int subbase = (threadIdx.x & 15) * HPAD;
    int tid = blockIdx.x * THREADS + threadIdx.x;
    int stride = HB * THREADS;
    int n4 = n >> 2;
    const float4* p4 = (const float4*)pnl;
    for (int i = tid; i < n4; i += stride) {
        float4 v = p4[i];
        float l[4] = {-v.x, -v.y, -v.z, -v.w};
        #pragma unroll
        for (int k = 0; k < 4; ++k) {
            float x = (l[k] - t_min) * inv_dt;
            int b = (int)x;
            b = b < 0 ? 0 : (b > T_SAMPLES - 1 ? T_SAMPLES - 1 : b);
            unsigned of = (unsigned)(fminf(x - (float)b, 0.99987793f) * 8192.0f);
            atomicAdd(&h[subbase + b], (1u << CNT_SHIFT) | of);
        }
    }
    for (int i = (n4 << 2) + tid; i < n; i += stride) {
        float x = (-pnl[i] - t_min) * inv_dt;
        int b = (int)x;
        b = b < 0 ? 0 : (b > T_SAMPLES - 1 ? T_SAMPLES - 1 : b);
        unsigned of = (unsigned)(fminf(x - (float)b, 0.99987793f) * 8192.0f);
        atomicAdd(&h[subbase + b], (1u << CNT_SHIFT) | of);
    }
    __syncthreads();

    // merge 16 subs -> one packed u64 atomic into this block's slot copy
    unsigned long long* slots = (unsigned long long*)ws + SLOTS64;
    if (threadIdx.x < T_SAMPLES) {
        unsigned cnt = 0u, ofs = 0u;
        #pragma unroll
        for (int s = 0; s < NSUB; ++s) {
            unsigned p = h[s * HPAD + threadIdx.x];
            cnt += p >> CNT_SHIFT;
            ofs += p & OFS_MASK;
        }
        atomicAdd(&slots[(blockIdx.x & (NCOPY - 1)) * SLOT_STRIDE + threadIdx.x],
                  ((unsigned long long)cnt << GSHIFT) | (unsigned long long)ofs);
    }
    __syncthreads();

    if (threadIdx.x == 0) {
        __threadfence();
        unsigned prev = atomicAdd((unsigned*)ws, 1u);
        amLast = (prev == HB - 1);
    }
    __syncthreads();
    if (!amLast) return;
    __threadfence();

    // finale: 2 threads/bin x 32 independent agent-scope loads (6400 total)
    {
        int g = threadIdx.x >> 1, q = threadIdx.x & 1;
        unsigned long long c64 = 0ull, o64 = 0ull;
        if (g < T_SAMPLES) {
            #pragma unroll 8
            for (int c = q; c < NCOPY; c += 2) {
                unsigned long long p = __hip_atomic_load(
                    &slots[c * SLOT_STRIDE + g], __ATOMIC_RELAXED, __HIP_MEMORY_SCOPE_AGENT);
                c64 += p >> GSHIFT;
                o64 += p & GMASK;
            }
        }
        c64 += __shfl_down(c64, 1, 2);
        o64 += __shfl_down(o64, 1, 2);
        if (g < T_SAMPLES && q == 0) { dcnt[g] = (double)c64; dofs[g] = (double)o64; }
    }
    __syncthreads();

    const float dt = range / (float)(T_SAMPLES - 1);
    float cvar = INFINITY;
    int j = threadIdx.x;
    if (j < T_SAMPLES) {
        double O = 0.0, W = 0.0;
        for (int k = j; k < T_SAMPLES; ++k) {
            O += dofs[k];
            W += (double)(k - j) * dcnt[k];
        }
        // S(t_j) = dt * ( sum(frac)/2^13 + sum (k-j)*C_k )
        double S = (double)dt * (O * (1.0 / 8192.0) + W);
        float tj = (j == T_SAMPLES - 1) ? t_max : t_min + (float)j * dt;
        cvar = tj + (float)(S * (20.0 / (double)n));
    }
    #pragma unroll
    for (int off = 32; off > 0; off >>= 1)
        cvar = fminf(cvar, __shfl_down(cvar, off, 64));
    int lane = threadIdx.x & 63, wid = threadIdx.x >> 6;
    if (lane == 0) sred[wid] = cvar;
    __syncthreads();
    if (threadIdx.x == 0) {
        float m = sred[0];
        for (int w = 1; w < NWAVES; ++w) m = fminf(m, sred[w]);
        out[0] = m;
    }
}

extern "C" void kernel_launch(void* const* d_in, const int* in_sizes, int n_in,
                              void* d_out, int out_size, void* d_ws, size_t ws_size,
                              hipStream_t stream) {
    const float* pnl = (const float*)d_in[0];
    int n = in_sizes[0];
    float* ws = (float*)d_ws;
    float* out = (float*)d_out;

    cvar_pass1<<<K1_BLOCKS, THREADS, 0, stream>>>(pnl, n, ws);
    cvar_pass2<<<HB, THREADS, 0, stream>>>(pnl, n, ws, out);
}

// Round 9
// 25.511 us; speedup vs baseline: 1.6561x; 1.4977x over previous
//
#include <hip/hip_runtime.h>
#include <math.h>

#define T_SAMPLES 100
#define K1_BLOCKS 1024
#define HB 1024           // hist blocks (R5-proven: 4/CU, 256 thr)
#define THREADS 256
#define NWAVES (THREADS / 64)
#define NSUB 16           // sub-histogram per lane&15 (4 lanes/wave share one)
#define HPAD 101          // odd stride -> 16 subs on distinct banks
#define CNT_SHIFT 23      // LDS pack (R5-proven): count bits[23:31], frac*2^15 bits[0:22]
#define OFS_MASK ((1u << 23) - 1u)
#define PART64 2048       // u64 index: block b's packed bins at [PART64 + b*104 + j]
#define BSTRIDE 104       // u64 per block region (832 B = 13 full lines)
#define GSHIFT 43         // global pack: cnt bits[43:63], ofs bits[0:42]
#define GMASK ((1ull << GSHIFT) - 1ull)
#define FINAL_D 110000    // double index: cnt[j] at +j, ofs[j] at +128+j
// ws footprint ~880 KB (ws is ~268 MB per harness fill sizes)

__global__ void __launch_bounds__(THREADS) cvar_pass1(const float* __restrict__ pnl,
                                                      int n, float* __restrict__ ws) {
    int tid = blockIdx.x * THREADS + threadIdx.x;
    int stride = gridDim.x * THREADS;
    float lmin = INFINITY, lmax = -INFINITY;
    int n4 = n >> 2;
    const float4* p4 = (const float4*)pnl;
    for (int i = tid; i < n4; i += stride) {
        float4 v = p4[i];
        lmin = fminf(lmin, fminf(fminf(-v.x, -v.y), fminf(-v.z, -v.w)));
        lmax = fmaxf(lmax, fmaxf(fmaxf(-v.x, -v.y), fmaxf(-v.z, -v.w)));
    }
    for (int i = (n4 << 2) + tid; i < n; i += stride) {
        float l = -pnl[i];
        lmin = fminf(lmin, l);
        lmax = fmaxf(lmax, l);
    }
    #pragma unroll
    for (int off = 32; off > 0; off >>= 1) {
        lmin = fminf(lmin, __shfl_down(lmin, off, 64));
        lmax = fmaxf(lmax, __shfl_down(lmax, off, 64));
    }
    __shared__ float smin[NWAVES], smax[NWAVES];
    int lane = threadIdx.x & 63, wid = threadIdx.x >> 6;
    if (lane == 0) { smin[wid] = lmin; smax[wid] = lmax; }
    __syncthreads();
    if (threadIdx.x == 0) {
        float a = smin[0], b = smax[0];
        for (int w = 1; w < NWAVES; ++w) { a = fminf(a, smin[w]); b = fmaxf(b, smax[w]); }
        ws[16 + blockIdx.x] = a;
        ws[16 + K1_BLOCKS + blockIdx.x] = b;
    }
}

__device__ __forceinline__ void reduce_minmax_partials(const float* __restrict__ ws,
                                                       float* s_tmin, float* s_tmax,
                                                       float* smin, float* smax) {
    float lmin = INFINITY, lmax = -INFINITY;
    for (int i = threadIdx.x; i < K1_BLOCKS; i += blockDim.x) {
        lmin = fminf(lmin, ws[16 + i]);
        lmax = fmaxf(lmax, ws[16 + K1_BLOCKS + i]);
    }
    #pragma unroll
    for (int off = 32; off > 0; off >>= 1) {
        lmin = fminf(lmin, __shfl_down(lmin, off, 64));
        lmax = fmaxf(lmax, __shfl_down(lmax, off, 64));
    }
    int lane = threadIdx.x & 63, wid = threadIdx.x >> 6;
    if (lane == 0) { smin[wid] = lmin; smax[wid] = lmax; }
    __syncthreads();
    if (threadIdx.x == 0) {
        float a = smin[0], b = smax[0];
        int nw = blockDim.x >> 6;
        for (int w = 1; w < nw; ++w) { a = fminf(a, smin[w]); b = fmaxf(b, smax[w]); }
        *s_tmin = a;
        *s_tmax = b;
    }
    __syncthreads();
}

__global__ void __launch_bounds__(THREADS) cvar_pass2(const float* __restrict__ pnl,
                                                      int n, float* __restrict__ ws) {
    __shared__ unsigned h[NSUB * HPAD];
    __shared__ float smin[NWAVES], smax[NWAVES];
    __shared__ float s_tmin, s_tmax;

    for (int i = threadIdx.x; i < NSUB * HPAD; i += THREADS) h[i] = 0u;
    reduce_minmax_partials(ws, &s_tmin, &s_tmax, smin, smax);

    const float t_min = s_tmin, t_max = s_tmax;
    const float range = t_max - t_min;
    const float inv_dt = (range > 0.0f) ? (float)(T_SAMPLES - 1) / range : 0.0f;

    // R5-proven LDS histogram: <=8 elems/thread, sub keyed by lane&15
    const int subbase = (threadIdx.x & 15) * HPAD;
    int tid = blockIdx.x * THREADS + threadIdx.x;
    int stride = HB * THREADS;
    int n4 = n >> 2;
    const float4* p4 = (const float4*)pnl;
    for (int i = tid; i < n4; i += stride) {
        float4 v = p4[i];
        float l[4] = {-v.x, -v.y, -v.z, -v.w};
        #pragma unroll
        for (int k = 0; k < 4; ++k) {
            float x = (l[k] - t_min) * inv_dt;
            int b = (int)x;
            b = b < 0 ? 0 : (b > T_SAMPLES - 1 ? T_SAMPLES - 1 : b);
            unsigned of = (unsigned)(fminf(x - (float)b, 0.99996948f) * 32768.0f);
            atomicAdd(&h[subbase + b], (1u << CNT_SHIFT) | of);
        }
    }
    for (int i = (n4 << 2) + tid; i < n; i += stride) {
        float x = (-pnl[i] - t_min) * inv_dt;
        int b = (int)x;
        b = b < 0 ? 0 : (b > T_SAMPLES - 1 ? T_SAMPLES - 1 : b);
        unsigned of = (unsigned)(fminf(x - (float)b, 0.99996948f) * 32768.0f);
        atomicAdd(&h[subbase + b], (1u << CNT_SHIFT) | of);
    }
    __syncthreads();

    // merge 16 subs -> ONE packed u64 per bin, CONTIGUOUS per-block store
    // (13 full cache lines per block; transpose cost moved to binreduce reads)
    if (threadIdx.x < T_SAMPLES) {
        unsigned cnt = 0u, ofs = 0u;
        #pragma unroll
        for (int s = 0; s < NSUB; ++s) {
            unsigned p = h[s * HPAD + threadIdx.x];
            cnt += p >> CNT_SHIFT;
            ofs += p & OFS_MASK;
        }
        ((unsigned long long*)ws)[PART64 + (size_t)blockIdx.x * BSTRIDE + threadIdx.x] =
            ((unsigned long long)cnt << GSHIFT) | (unsigned long long)ofs;
    }
}

// 100 blocks: block j reduces bin j across 1024 block-regions (strided, MLP-covered)
__global__ void __launch_bounds__(THREADS) cvar_binreduce(float* __restrict__ ws) {
    const unsigned long long* part = (const unsigned long long*)ws + PART64;
    unsigned long long c64 = 0ull, o64 = 0ull;
    for (int b = threadIdx.x; b < HB; b += THREADS) {
        unsigned long long p = part[(size_t)b * BSTRIDE + blockIdx.x];
        c64 += p >> GSHIFT;
        o64 += p & GMASK;
    }
    #pragma unroll
    for (int off = 32; off > 0; off >>= 1) {
        c64 += __shfl_down(c64, off, 64);
        o64 += __shfl_down(o64, off, 64);
    }
    __shared__ unsigned long long sc[NWAVES], so[NWAVES];
    int lane = threadIdx.x & 63, wid = threadIdx.x >> 6;
    if (lane == 0) { sc[wid] = c64; so[wid] = o64; }
    __syncthreads();
    if (threadIdx.x == 0) {
        unsigned long long C = sc[0], O = so[0];
        for (int w = 1; w < NWAVES; ++w) { C += sc[w]; O += so[w]; }
        ((double*)ws)[FINAL_D + blockIdx.x] = (double)C;
        ((double*)ws)[FINAL_D + 128 + blockIdx.x] = (double)O;
    }
}

__global__ void __launch_bounds__(128) cvar_final(const float* __restrict__ ws,
                                                  float* __restrict__ out, int n) {
    __shared__ float smin[2], smax[2];
    __shared__ float s_tmin, s_tmax;
    __shared__ double dcnt[T_SAMPLES], dofs[T_SAMPLES];
    __shared__ float sred[2];

    reduce_minmax_partials(ws, &s_tmin, &s_tmax, smin, smax);
    const float t_min = s_tmin, t_max = s_tmax;
    const float range = t_max - t_min;
    const float dt = range / (float)(T_SAMPLES - 1);

    int j = threadIdx.x;
    if (j < T_SAMPLES) {
        dcnt[j] = ((const double*)ws)[FINAL_D + j];
        dofs[j] = ((const double*)ws)[FINAL_D + 128 + j];
    }
    __syncthreads();

    float cvar = INFINITY;
    if (j < T_SAMPLES) {
        double O = 0.0, W = 0.0;
        for (int k = j; k < T_SAMPLES; ++k) {
            O += dofs[k];
            W += (double)(k - j) * dcnt[k];
        }
        // S(t_j) = dt * ( sum(frac)/2^15 + sum (k-j)*C_k )
        double S = (double)dt * (O * (1.0 / 32768.0) + W);
        float tj = (j == T_SAMPLES - 1) ? t_max : t_min + (float)j * dt;
        cvar = tj + (float)(S * (20.0 / (double)n));
    }
    #pragma unroll
    for (int off = 32; off > 0; off >>= 1)
        cvar = fminf(cvar, __shfl_down(cvar, off, 64));
    int lane = threadIdx.x & 63, wid = threadIdx.x >> 6;
    if (lane == 0) sred[wid] = cvar;
    __syncthreads();
    if (threadIdx.x == 0) out[0] = fminf(sred[0], sred[1]);
}

extern "C" void kernel_launch(void* const* d_in, const int* in_sizes, int n_in,
                              void* d_out, int out_size, void* d_ws, size_t ws_size,
                              hipStream_t stream) {
    const float* pnl = (const float*)d_in[0];
    int n = in_sizes[0];
    float* ws = (float*)d_ws;
    float* out = (float*)d_out;

    cvar_pass1<<<K1_BLOCKS, THREADS, 0, stream>>>(pnl, n, ws);
    cvar_pass2<<<HB, THREADS, 0, stream>>>(pnl, n, ws);
    cvar_binreduce<<<T_SAMPLES, THREADS, 0, stream>>>(ws);
    cvar_final<<<1, 128, 0, stream>>>(ws, out, n);
}